// Round 1
// baseline (236.615 us; speedup 1.0000x reference)
//
#include <hip/hip_runtime.h>

#define POOL 7
#define IMG_W 256
#define IMG_C 512
#define NUM_ROIS 1024

typedef float f4 __attribute__((ext_vector_type(4)));

// ---------------- kernel 1: spatial counting-sort of ROI indices ----------
// Key = 32x32-px tile of (x1,y1), row-major: 8x8 = 64 buckets. One block,
// 1024 threads. Within-bucket order is nondeterministic (LDS atomics) —
// harmless: main kernel writes out[roi] exactly once, any order.
// NEW: also emits the pre-gathered sorted descriptor array sdesc so the
// pool kernel has NO dependent order->rois pointer chase.
__global__ __launch_bounds__(1024) void sort_rois_kernel(
    const int* __restrict__ rois, int* __restrict__ order,
    int4* __restrict__ sdesc)
{
    __shared__ int hist[64];
    __shared__ int base[64];
    const int tid = threadIdx.x;

    if (tid < 64) hist[tid] = 0;
    __syncthreads();

    const int4 rb = ((const int4*)rois)[tid];
    const int key = ((rb.y >> 5) << 3) | (rb.x >> 5);
    const int rank = atomicAdd(&hist[key], 1);
    __syncthreads();

    // wave-parallel exclusive prefix scan over the 64 buckets (one wave)
    if (tid < 64) {
        const int v = hist[tid];
        int inc = v;
#pragma unroll
        for (int d = 1; d < 64; d <<= 1) {
            const int n = __shfl_up(inc, d, 64);
            if (tid >= d) inc += n;
        }
        base[tid] = inc - v;
    }
    __syncthreads();

    const int dst = base[key] + rank;
    order[dst] = tid;       // sorted position -> original roi index
    sdesc[dst] = rb;        // sorted position -> box, pre-gathered
}

// ---------------- kernel 2: ROI pooling over the sorted order -------------
// Block = (sorted-roi, py). XCD i (bid&7) owns sorted chunk [i*128,(i+1)*128):
// consecutive blocks on one XCD touch spatially adjacent ROIs (py-major, so
// the 7 rows of one ROI are consecutive on the same XCD), keeping the 4MB
// per-XCD L2 on a sliding spatial window.
// Descriptor fetch is now TWO INDEPENDENT uniform scalar loads (sdesc +
// order), both L2-resident (20 KB total), instead of a 2-hop dependent
// chase — blocks start issuing image loads one memory round-trip sooner.
__global__ __launch_bounds__(128) void roi_pool_kernel(
    const float* __restrict__ img,
    const int4*  __restrict__ sdesc,
    const int*   __restrict__ order,
    float*       __restrict__ out)
{
    const int bid  = blockIdx.x;           // 0..7167
    const int xcd  = bid & 7;
    const int slot = bid >> 3;             // 0..895
    const int sloc = slot / POOL;          // 0..127: position within chunk
    const int py   = slot - sloc * POOL;   // 0..6
    const int sidx = xcd * (NUM_ROIS / 8) + sloc;   // sorted position

    // independent uniform loads — single latency exposure, scalar pipe
    const int4 rb  = sdesc[sidx];
    const int  ro  = order[sidx];

    const int x1  = __builtin_amdgcn_readfirstlane(rb.x);
    const int y1  = __builtin_amdgcn_readfirstlane(rb.y);
    const int x2  = __builtin_amdgcn_readfirstlane(rb.z);
    const int y2  = __builtin_amdgcn_readfirstlane(rb.w);
    const int roi = __builtin_amdgcn_readfirstlane(ro);

    const float h = (float)(y2 - y1);
    const float w = (float)(x2 - x1);
    const float sy = h / (float)POOL;      // reference numerics: h/P, then py*(h/P)
    const float sx = w / (float)POOL;

    const float ys = (float)py * sy;
    const int   y0 = (int)floorf(ys);
    const int   y1i = min(y0 + 1, max(y2 - y1 - 1, 0));
    const float wy = ys - (float)y0;

    const size_t rowstride = (size_t)IMG_W * IMG_C;
    const float* row0 = img + (size_t)(y1 + y0)  * rowstride;
    const float* row1 = img + (size_t)(y1 + y1i) * rowstride;

    const int t = threadIdx.x;             // 0..127
    const int cmax = max(x2 - x1 - 1, 0);

    f4* obase = (f4*)out + ((size_t)roi * (POOL * POOL) + (size_t)py * POOL) * (IMG_C / 4) + t;

#pragma unroll
    for (int px = 0; px < POOL; ++px) {
        const float xs = (float)px * sx;
        const int   x0 = (int)floorf(xs);
        const int   x1i = min(x0 + 1, cmax);
        const float wx = xs - (float)x0;
        const int c0 = x1 + x0, c1 = x1 + x1i;

        const f4 v00 = ((const f4*)(row0 + (size_t)c0 * IMG_C))[t];
        const f4 v01 = ((const f4*)(row0 + (size_t)c1 * IMG_C))[t];
        const f4 v10 = ((const f4*)(row1 + (size_t)c0 * IMG_C))[t];
        const f4 v11 = ((const f4*)(row1 + (size_t)c1 * IMG_C))[t];

        const float w00 = (1.0f - wy) * (1.0f - wx);
        const float w01 = (1.0f - wy) * wx;
        const float w10 = wy * (1.0f - wx);
        const float w11 = wy * wx;

        f4 o = v00 * w00 + v01 * w01 + v10 * w10 + v11 * w11;
        __builtin_nontemporal_store(o, obase + px * (IMG_C / 4));
    }
}

extern "C" void kernel_launch(void* const* d_in, const int* in_sizes, int n_in,
                              void* d_out, int out_size, void* d_ws, size_t ws_size,
                              hipStream_t stream) {
    const float* img  = (const float*)d_in[0];
    const int*   rois = (const int*)d_in[1];
    float* out = (float*)d_out;
    int*  order = (int*)d_ws;                         // 1024 ints
    int4* sdesc = (int4*)((char*)d_ws + 4096);        // 1024 int4, 16B-aligned

    sort_rois_kernel<<<1, 1024, 0, stream>>>(rois, order, sdesc);
    roi_pool_kernel<<<NUM_ROIS * POOL, 128, 0, stream>>>(img, sdesc, order, out);
}

// Round 2
// 235.410 us; speedup vs baseline: 1.0051x; 1.0051x over previous
//
#include <hip/hip_runtime.h>

#define POOL 7
#define IMG_W 256
#define IMG_C 512
#define NUM_ROIS 1024

typedef float f4 __attribute__((ext_vector_type(4)));

// ---------------- kernel 1: spatial counting-sort of ROI indices ----------
// Key = 32x32-px tile of (x1,y1), row-major: 8x8 = 64 buckets. One block,
// 1024 threads. Within-bucket order nondeterministic (LDS atomics) —
// harmless: main kernel writes out[roi] exactly once, any order.
// Emits pre-gathered sorted descriptors; roi index packed into .w
// ((y2<<10)|roi — y2<=256 fits 9 bits, roi<1024 fits 10) so the pool
// kernel needs exactly ONE uniform 16B load per block.
__global__ __launch_bounds__(1024) void sort_rois_kernel(
    const int* __restrict__ rois, int4* __restrict__ sdesc)
{
    __shared__ int hist[64];
    __shared__ int base[64];
    const int tid = threadIdx.x;

    if (tid < 64) hist[tid] = 0;
    __syncthreads();

    const int4 rb = ((const int4*)rois)[tid];
    const int key = ((rb.y >> 5) << 3) | (rb.x >> 5);
    const int rank = atomicAdd(&hist[key], 1);
    __syncthreads();

    // wave-parallel exclusive prefix scan over the 64 buckets (one wave)
    if (tid < 64) {
        const int v = hist[tid];
        int inc = v;
#pragma unroll
        for (int d = 1; d < 64; d <<= 1) {
            const int n = __shfl_up(inc, d, 64);
            if (tid >= d) inc += n;
        }
        base[tid] = inc - v;
    }
    __syncthreads();

    const int dst = base[key] + rank;
    sdesc[dst] = (int4){rb.x, rb.y, rb.z, (rb.w << 10) | tid};
}

// ---------------- kernel 2: ROI pooling, max-MLP two-phase form -----------
// Block = (sorted-roi, py), 128 threads (2 waves), XCD-chunked as before.
// Phase A: issue ALL 28 pixel loads (7 px x 4 taps) into statically-
// indexed register arrays — nothing between the loads, so the memory
// pipe sees 28 independent 1KB requests per wave back-to-back.
// Phase B: weighted sums + NT stores.
// __launch_bounds__(128, 2): min 2 waves/EU -> VGPR cap 256, so the
// ~112 VGPRs of load destinations don't spill and don't get serialized
// by the compiler's default occupancy heuristic.
__global__ __launch_bounds__(128, 2) void roi_pool_kernel(
    const float* __restrict__ img,
    const int4*  __restrict__ sdesc,
    float*       __restrict__ out)
{
    const int bid  = blockIdx.x;           // 0..7167
    const int xcd  = bid & 7;
    const int slot = bid >> 3;             // 0..895
    const int sloc = slot / POOL;          // 0..127: position within chunk
    const int py   = slot - sloc * POOL;   // 0..6
    const int sidx = xcd * (NUM_ROIS / 8) + sloc;   // sorted position

    const int4 rb = sdesc[sidx];
    const int x1  = __builtin_amdgcn_readfirstlane(rb.x);
    const int y1  = __builtin_amdgcn_readfirstlane(rb.y);
    const int x2  = __builtin_amdgcn_readfirstlane(rb.z);
    const int w2  = __builtin_amdgcn_readfirstlane(rb.w);
    const int y2  = w2 >> 10;
    const int roi = w2 & 1023;

    const float h = (float)(y2 - y1);
    const float w = (float)(x2 - x1);
    const float sy = h / (float)POOL;      // reference numerics: h/P, then py*(h/P)
    const float sx = w / (float)POOL;

    const float ys = (float)py * sy;
    const int   y0 = (int)floorf(ys);
    const int   y1i = min(y0 + 1, max(y2 - y1 - 1, 0));
    const float wy = ys - (float)y0;

    const size_t rowstride = (size_t)IMG_W * IMG_C;
    const float* row0 = img + (size_t)(y1 + y0)  * rowstride;
    const float* row1 = img + (size_t)(y1 + y1i) * rowstride;

    const int t = threadIdx.x;             // 0..127
    const int cmax = max(x2 - x1 - 1, 0);

    // ---- scalar phase: all column indices + weights (uniform per block)
    int   c0a[POOL], c1a[POOL];
    float wxa[POOL];
#pragma unroll
    for (int px = 0; px < POOL; ++px) {
        const float xs = (float)px * sx;
        const int   x0 = (int)floorf(xs);
        c0a[px] = x1 + x0;
        c1a[px] = x1 + min(x0 + 1, cmax);
        wxa[px] = xs - (float)x0;
    }

    // ---- phase A: issue all 28 loads, fully clustered, static indices
    f4 v00[POOL], v01[POOL], v10[POOL], v11[POOL];
#pragma unroll
    for (int px = 0; px < POOL; ++px) {
        v00[px] = ((const f4*)(row0 + (size_t)c0a[px] * IMG_C))[t];
        v01[px] = ((const f4*)(row0 + (size_t)c1a[px] * IMG_C))[t];
        v10[px] = ((const f4*)(row1 + (size_t)c0a[px] * IMG_C))[t];
        v11[px] = ((const f4*)(row1 + (size_t)c1a[px] * IMG_C))[t];
    }

    // ---- phase B: weighted sums + NT stores
    f4* obase = (f4*)out + ((size_t)roi * (POOL * POOL) + (size_t)py * POOL) * (IMG_C / 4) + t;
#pragma unroll
    for (int px = 0; px < POOL; ++px) {
        const float wx = wxa[px];
        const float w00 = (1.0f - wy) * (1.0f - wx);
        const float w01 = (1.0f - wy) * wx;
        const float w10 = wy * (1.0f - wx);
        const float w11 = wy * wx;
        f4 o = v00[px] * w00 + v01[px] * w01 + v10[px] * w10 + v11[px] * w11;
        __builtin_nontemporal_store(o, obase + px * (IMG_C / 4));
    }
}

extern "C" void kernel_launch(void* const* d_in, const int* in_sizes, int n_in,
                              void* d_out, int out_size, void* d_ws, size_t ws_size,
                              hipStream_t stream) {
    const float* img  = (const float*)d_in[0];
    const int*   rois = (const int*)d_in[1];
    float* out = (float*)d_out;
    int4* sdesc = (int4*)d_ws;             // 1024 int4, rewritten every call

    sort_rois_kernel<<<1, 1024, 0, stream>>>(rois, sdesc);
    roi_pool_kernel<<<NUM_ROIS * POOL, 128, 0, stream>>>(img, sdesc, out);
}